// Round 9
// baseline (593.637 us; speedup 1.0000x reference)
//
#include <hip/hip_runtime.h>

#define EPSF 1e-8f
#define RCUT 4.8f
#define NB 64
#define NSEL 20

// ---- weights blob layout (float offsets inside wsW) ----
#define OW0T 0        // 64 rows x 16 (transposed W0, row-padded; col 15 unwritten)
#define OB0  1024     // 64
#define OB1  1088     // 64
#define OW2  1152     // 64
#define OB2  1216     // 1
#define OAQ  1220     // 3: f1^2+eps
#define OCQ  1224     // 3: f2^2+eps
#define OLG  1228     // 3: log(aq)
#define OW1  1232     // 64x64
#define WSWN 5328     // total floats

// sC layout: sC[t] = wsW[OB0 + t]  =>  index = blob offset - 1024.
// R11 FIX: R10 had SCQ=196/SLG=199 which aliased aq and a blob GAP word
// (wsW[1223], uninitialized) -> wrong exponents + garbage log => absmax 15.8.
#define SB0 0          // 1024-1024
#define SB1 64         // 1088-1024
#define SW2 128        // 1152-1024
#define SB2 192        // 1216-1024
#define SCQ 200        // 1224-1024
#define SLG 204        // 1228-1024

__device__ __forceinline__ float fast_tanh(float x) {
    float e = __expf(2.0f * x);
    return 1.0f - __fdividef(2.0f, e + 1.0f);
}

// ---------------- Kernel A: norms + select 20 nearest + pre-gather ----------
extern "C" __global__ void __launch_bounds__(256)
sel_kernel(const float* __restrict__ dr, const float* __restrict__ n_or,
           const float* __restrict__ W0, const float* __restrict__ b0,
           const float* __restrict__ W1, const float* __restrict__ b1,
           const float* __restrict__ W2, const float* __restrict__ b2,
           const float* __restrict__ f1, const float* __restrict__ f2,
           float* __restrict__ ws_R, float* __restrict__ ws_fc,
           float* __restrict__ ws_F, int* __restrict__ ws_idx,
           float* __restrict__ ws_ndn, float* __restrict__ ws_nor,
           float* __restrict__ wsW)
{
    __shared__ float R_s[256];
    const int t = threadIdx.x;
    const int g = t >> 6;
    const int j = t & 63;
    const int b = blockIdx.x * 4 + g;

    const float* p = dr + ((size_t)b * NB + j) * 3;
    float x = p[0] + EPSF, y = p[1] + EPSF, z = p[2] + EPSF;
    float R = sqrtf(x * x + y * y + z * z);
    R_s[t] = R;
    __syncthreads();

    int rank = 0;
    const float* grp = R_s + g * 64;
    #pragma unroll 8
    for (int k = 0; k < 64; ++k) {
        float Rk = grp[k];
        rank += (Rk < R || (Rk == R && k < j)) ? 1 : 0;
    }

    float fc = 0.0f;
    if (rank < NSEL) {
        fc = (R > RCUT) ? 0.0f
                        : (0.5f * __cosf(3.14159265358979323846f * R / RCUT) + 0.5f);
        size_t o = (size_t)b * NSEL + rank;
        ws_R[o]  = R;
        ws_fc[o] = fc;
        if (ws_idx) ws_idx[o] = j;
        float inv = 1.0f / R;
        ws_ndn[o * 3 + 0] = x * inv;
        ws_ndn[o * 3 + 1] = y * inv;
        ws_ndn[o * 3 + 2] = z * inv;
    }

    if (ws_nor) {
        const float* np = n_or + ((size_t)b * NB + j) * 9;
        float r[9];
        #pragma unroll
        for (int q = 0; q < 9; ++q) r[q] = np[q];
        if (rank < NSEL) {
            float* dst = ws_nor + ((size_t)b * NSEL + rank) * 9;
            #pragma unroll
            for (int q = 0; q < 9; ++q) dst[q] = r[q];
        }
    }

    float F = fc;
    for (int off = 32; off > 0; off >>= 1) F += __shfl_xor(F, off, 64);
    if (j == 0) ws_F[b] = F;

    if (blockIdx.x == 0) {
        for (int i = t; i < 15 * 64; i += 256) {
            int k = i >> 6, jj = i & 63;
            wsW[OW0T + jj * 16 + k] = W0[i];
        }
        for (int i = t; i < 64 * 64; i += 256)
            wsW[OW1 + i] = W1[i];
        if (t < 64) {
            wsW[OB0 + t] = b0[t];
            wsW[OB1 + t] = b1[t];
            wsW[OW2 + t] = W2[t];
        }
        if (t == 0) wsW[OB2] = b2[0];
        if (t < 3) {
            float a = f1[t] * f1[t] + EPSF;
            float c = f2[t] * f2[t] + EPSF;
            wsW[OAQ + t] = a;
            wsW[OCQ + t] = c;
            wsW[OLG + t] = __logf(a);
        }
    }
}

// ---------------- Kernel B: lane=i-dim, wave=half-b (10 pairs) --------------
// R10 design (R11 = R10 + sC offset fix). R0-R9 evidence: thread-per-pair
// designs are pinned at ~13% per-wave VALU duty by the serialized scalar W1
// stream (SGPR-depth-capped K$ misses); wave count is register-capped
// (acc[64]); splitting pairs across threads duplicates the serial W0 chain
// (R9: +67% work). Escape: lane l owns h2-dim i=l; W1 in LDS [64][65]
// (pad 65 -> banks (j+l)%32 fwd, (l+i)%32 bwd = 2/bank, conflict-free);
// h1 computed ONCE (lane l owns j=l) into LDS, consumed as broadcasts;
// acc[10] VGPRs. 8 waves/block (4 b), ~75KB LDS -> 2 blocks/CU.
template<bool PRE>
__global__ void __launch_bounds__(512, 4)
energy_kernel_t(const float* __restrict__ orientation,
                const float* __restrict__ n_or,          // !PRE only
                const float* __restrict__ wsW,
                const float* __restrict__ wsD,           // = ws_R base
                const int*   __restrict__ ws_idx_fb,     // !PRE only
                const float* __restrict__ ws_ndn_fb,     // !PRE only
                float* __restrict__ outBase, const int Bn)
{
    __shared__ float sW1[64 * 65];     // 16.64 KB
    __shared__ float sW0T[64 * 17];    // 4.35 KB
    __shared__ float sC[208];          // b0|b1|W2|b2|(aq)|cq|lg
    __shared__ float h1b[8][64 * 12];  // per-wave h1 (then dz1)  24.6 KB
    __shared__ float dzb[8][64 * 12];  // per-wave dz2            24.6 KB
    __shared__ float featb[8][10 * 16];// per-wave feat (then dfeat) 5.1 KB
    __shared__ float dz3b[8][10];
    __shared__ float sG[4][2][12];
    __shared__ float sPsum[4][2];

    const int t    = threadIdx.x;
    const int wave = t >> 6;           // 0..7
    const int lane = t & 63;
    const int bb   = wave >> 1;        // local b 0..3
    const int w    = wave & 1;         // which 10-pair half
    const int b    = blockIdx.x * 4 + bb;

    // ---- stage weights into LDS (block-wide) ----
    for (int i = t; i < 64 * 64; i += 512) {
        int r = i >> 6, c = i & 63;
        sW1[r * 65 + c] = wsW[OW1 + i];
    }
    for (int i = t; i < 64 * 16; i += 512) {
        int r = i >> 4, c = i & 15;
        sW0T[r * 17 + c] = wsW[OW0T + i];   // c==15 junk, never used in FMAs
    }
    if (t < 208) sC[t] = wsW[OB0 + t];
    __syncthreads();

    // derived data pointers
    const float* ws_R   = wsD;
    const float* ws_fc  = wsD + (size_t)Bn * NSEL;
    const float* ws_F   = wsD + (size_t)Bn * (2 * NSEL);
    const float* ws_ndn = PRE ? (wsD + (size_t)Bn * (2 * NSEL + 1)) : ws_ndn_fb;
    const float* ws_nor = wsD + (size_t)Bn * (2 * NSEL + 1 + 3 * NSEL);

    const int g = lane;                // pair slot for divergent phases
    const size_t o = (size_t)b * NSEL + w * 10 + g;
    const float Fb = ws_F[b];          // wave-uniform

    float* myH1   = &h1b[wave][0];     // [64 j][12]
    float* myDz   = &dzb[wave][0];     // [64 i][12]
    float* myFeat = &featb[wave][0];   // [10 g][16]

    // ---- ph1: per-pair loads + feat (lanes 0..9) ----
    float O[9], Nr[9], nd0 = 0.f, nd1 = 0.f, nd2 = 0.f, Rv = 0.f, fcv = 0.f;
    if (lane < 10) {
        nd0 = ws_ndn[o * 3 + 0];
        nd1 = ws_ndn[o * 3 + 1];
        nd2 = ws_ndn[o * 3 + 2];
        Rv  = ws_R[o];
        fcv = ws_fc[o];
        const float* Op = orientation + (size_t)b * 9;
        #pragma unroll
        for (int i = 0; i < 9; ++i) O[i] = Op[i];
        if (PRE) {
            const float* Np = ws_nor + o * 9;
            #pragma unroll
            for (int i = 0; i < 9; ++i) Nr[i] = Np[i];
        } else {
            const int idx = ws_idx_fb[o];
            const float* Np = n_or + ((size_t)b * NB + idx) * 9;
            #pragma unroll
            for (int i = 0; i < 9; ++i) Nr[i] = Np[i];
        }
        float feat[15];
        #pragma unroll
        for (int h = 0; h < 3; ++h)
            feat[h] = nd0 * O[h] + nd1 * O[3 + h] + nd2 * O[6 + h];
        #pragma unroll
        for (int h = 0; h < 3; ++h)
            feat[3 + h] = nd0 * Nr[h] + nd1 * Nr[3 + h] + nd2 * Nr[6 + h];
        #pragma unroll
        for (int l = 0; l < 3; ++l)
            #pragma unroll
            for (int m = 0; m < 3; ++m)
                feat[6 + l * 3 + m] = O[l] * Nr[m] + O[3 + l] * Nr[3 + m] + O[6 + l] * Nr[6 + m];
        #pragma unroll
        for (int k = 0; k < 15; ++k) myFeat[g * 16 + k] = feat[k];
    }

    // ---- ph2: h1[j=lane][g] for all 10 pairs ----
    float w0r[15];
    #pragma unroll
    for (int k = 0; k < 15; ++k) w0r[k] = sW0T[lane * 17 + k];
    const float b0l = sC[SB0 + lane];
    {
        float hbuf[10];
        #pragma unroll
        for (int gg = 0; gg < 10; ++gg) {
            const float4 f0 = *(const float4*)&myFeat[gg * 16 + 0];
            const float4 f1 = *(const float4*)&myFeat[gg * 16 + 4];
            const float4 f2 = *(const float4*)&myFeat[gg * 16 + 8];
            const float4 f3 = *(const float4*)&myFeat[gg * 16 + 12];
            float z = b0l;
            z = fmaf(f0.x, w0r[0], z);  z = fmaf(f0.y, w0r[1], z);
            z = fmaf(f0.z, w0r[2], z);  z = fmaf(f0.w, w0r[3], z);
            z = fmaf(f1.x, w0r[4], z);  z = fmaf(f1.y, w0r[5], z);
            z = fmaf(f1.z, w0r[6], z);  z = fmaf(f1.w, w0r[7], z);
            z = fmaf(f2.x, w0r[8], z);  z = fmaf(f2.y, w0r[9], z);
            z = fmaf(f2.z, w0r[10], z); z = fmaf(f2.w, w0r[11], z);
            z = fmaf(f3.x, w0r[12], z); z = fmaf(f3.y, w0r[13], z);
            z = fmaf(f3.z, w0r[14], z);
            hbuf[gg] = fast_tanh(z);
        }
        #pragma unroll
        for (int gg = 0; gg < 10; ++gg) myH1[lane * 12 + gg] = hbuf[gg];
    }

    // ---- ph3: z2[i=lane][g] = b1[i] + sum_j h1[j][g]*W1[j][i] ----
    float acc[10];
    {
        const float b1l = sC[SB1 + lane];
        #pragma unroll
        for (int gg = 0; gg < 10; ++gg) acc[gg] = b1l;
    }
    #pragma unroll 4
    for (int j = 0; j < 64; ++j) {
        const float wv = sW1[j * 65 + lane];
        const float4 hA = *(const float4*)&myH1[j * 12 + 0];
        const float4 hB = *(const float4*)&myH1[j * 12 + 4];
        const float4 hC = *(const float4*)&myH1[j * 12 + 8];
        acc[0] = fmaf(hA.x, wv, acc[0]); acc[1] = fmaf(hA.y, wv, acc[1]);
        acc[2] = fmaf(hA.z, wv, acc[2]); acc[3] = fmaf(hA.w, wv, acc[3]);
        acc[4] = fmaf(hB.x, wv, acc[4]); acc[5] = fmaf(hB.y, wv, acc[5]);
        acc[6] = fmaf(hB.z, wv, acc[6]); acc[7] = fmaf(hB.w, wv, acc[7]);
        acc[8] = fmaf(hC.x, wv, acc[8]); acc[9] = fmaf(hC.y, wv, acc[9]);
    }

    // ---- ph4: h2 = tanh, z3[g] = b2 + sum_i W2[i]*h2 (64-lane butterfly) ----
    const float w2l = sC[SW2 + lane];
    float z3v[10];
    #pragma unroll
    for (int gg = 0; gg < 10; ++gg) {
        float h2 = fast_tanh(acc[gg]);
        acc[gg] = h2;                       // keep h2 for backward
        float v = h2 * w2l;
        v += __shfl_xor(v, 1, 64);  v += __shfl_xor(v, 2, 64);
        v += __shfl_xor(v, 4, 64);  v += __shfl_xor(v, 8, 64);
        v += __shfl_xor(v, 16, 64); v += __shfl_xor(v, 32, 64);
        z3v[gg] = v + sC[SB2];
    }

    // ---- ph5: power-law per pair (lanes 0..9), dz3 -> LDS ----
    float psum = 0.f;
    if (lane < 10) {
        float z3 = z3v[0];
        #pragma unroll
        for (int gg = 1; gg < 10; ++gg) z3 = (g == gg) ? z3v[gg] : z3;
        const float enc = fast_tanh(z3);
        const float x = Rv - (enc * enc + EPSF);
        const float lx = __logf(x);
        float csum = 0.f;
        #pragma unroll
        for (int q = 0; q < 3; ++q) {
            float cq = sC[SCQ + q];
            float tq = __expf(-cq * (sC[SLG + q] + lx));
            psum += tq;
            csum = fmaf(cq, tq, csum);
        }
        const float dpdx = -__fdividef(csum, x);
        dz3b[wave][g] = Fb * dpdx * (-2.f * enc) * (1.f - enc * enc);
    }

    // ---- ph6: dz2[i=lane][g] -> LDS ----
    float d3[10];
    #pragma unroll
    for (int gg = 0; gg < 10; ++gg) d3[gg] = dz3b[wave][gg];
    #pragma unroll
    for (int gg = 0; gg < 10; ++gg) {
        float h2 = acc[gg];
        acc[gg] = d3[gg] * w2l * (1.f - h2 * h2);
    }
    *(float4*)&myDz[lane * 12 + 0] = make_float4(acc[0], acc[1], acc[2], acc[3]);
    *(float4*)&myDz[lane * 12 + 4] = make_float4(acc[4], acc[5], acc[6], acc[7]);
    *(float4*)&myDz[lane * 12 + 8] = make_float4(acc[8], acc[9], 0.f, 0.f);

    // ---- ph7: dha[j=lane][g] = sum_i dz2[i][g]*W1[j][i] ----
    float dha[10];
    #pragma unroll
    for (int gg = 0; gg < 10; ++gg) dha[gg] = 0.f;
    #pragma unroll 4
    for (int i = 0; i < 64; ++i) {
        const float wv = sW1[lane * 65 + i];
        const float4 dA = *(const float4*)&myDz[i * 12 + 0];
        const float4 dB = *(const float4*)&myDz[i * 12 + 4];
        const float4 dC = *(const float4*)&myDz[i * 12 + 8];
        dha[0] = fmaf(dA.x, wv, dha[0]); dha[1] = fmaf(dA.y, wv, dha[1]);
        dha[2] = fmaf(dA.z, wv, dha[2]); dha[3] = fmaf(dA.w, wv, dha[3]);
        dha[4] = fmaf(dB.x, wv, dha[4]); dha[5] = fmaf(dB.y, wv, dha[5]);
        dha[6] = fmaf(dB.z, wv, dha[6]); dha[7] = fmaf(dB.w, wv, dha[7]);
        dha[8] = fmaf(dC.x, wv, dha[8]); dha[9] = fmaf(dC.y, wv, dha[9]);
    }

    // ---- ph8: dz1[j=lane][g] = dha*(1-h1^2), overwrite h1 rows ----
    {
        const float4 hA = *(const float4*)&myH1[lane * 12 + 0];
        const float4 hB = *(const float4*)&myH1[lane * 12 + 4];
        const float4 hC = *(const float4*)&myH1[lane * 12 + 8];
        float hv[10] = {hA.x, hA.y, hA.z, hA.w, hB.x, hB.y, hB.z, hB.w, hC.x, hC.y};
        #pragma unroll
        for (int gg = 0; gg < 10; ++gg) {
            float z1 = dha[gg] * (1.f - hv[gg] * hv[gg]);
            myH1[lane * 12 + gg] = z1;
        }
    }

    // ---- ph9: dfeat[k][g] = sum_j dz1[j][g]*W0T[j][k] (60 lanes x 3 passes) ----
    {
        const int k9  = lane % 15;
        const int gl9 = lane / 15;         // 0..3 for lane<60
        #pragma unroll
        for (int pss = 0; pss < 3; ++pss) {
            const int g9 = pss * 4 + gl9;
            const bool act = (lane < 60) && (g9 < 10);
            float dacc = 0.f;
            if (act) {
                #pragma unroll 8
                for (int j = 0; j < 64; ++j)
                    dacc = fmaf(myH1[j * 12 + g9], sW0T[j * 17 + k9], dacc);
                myFeat[g9 * 16 + k9] = dacc;   // feat is dead; reuse as dfeat
            }
        }
    }

    // ---- ph10: per-pair epilogue (lanes 0..9) + wave reduction ----
    float comps[12];
    #pragma unroll
    for (int q = 0; q < 12; ++q) comps[q] = 0.f;
    if (lane < 10) {
        float df[15];
        {
            const float4 f0 = *(const float4*)&myFeat[g * 16 + 0];
            const float4 f1 = *(const float4*)&myFeat[g * 16 + 4];
            const float4 f2 = *(const float4*)&myFeat[g * 16 + 8];
            const float4 f3 = *(const float4*)&myFeat[g * 16 + 12];
            df[0]=f0.x; df[1]=f0.y; df[2]=f0.z; df[3]=f0.w;
            df[4]=f1.x; df[5]=f1.y; df[6]=f1.z; df[7]=f1.w;
            df[8]=f2.x; df[9]=f2.y; df[10]=f2.z; df[11]=f2.w;
            df[12]=f3.x; df[13]=f3.y; df[14]=f3.z;
        }
        #pragma unroll
        for (int k = 0; k < 3; ++k)
            comps[k] = df[0] * O[k * 3] + df[1] * O[k * 3 + 1] + df[2] * O[k * 3 + 2]
                     + df[3] * Nr[k * 3] + df[4] * Nr[k * 3 + 1] + df[5] * Nr[k * 3 + 2];
        float ndv[3] = {nd0, nd1, nd2};
        #pragma unroll
        for (int k = 0; k < 3; ++k)
            #pragma unroll
            for (int h = 0; h < 3; ++h)
                comps[3 + k * 3 + h] = df[h] * ndv[k];
        #pragma unroll
        for (int h = 0; h < 3; ++h)
            #pragma unroll
            for (int l = 0; l < 3; ++l) {
                float s = 0.f;
                #pragma unroll
                for (int m = 0; m < 3; ++m) s = fmaf(df[6 + l * 3 + m], Nr[h * 3 + m], s);
                comps[3 + h * 3 + l] += s;
            }
    }
    // 16-lane-group butterfly (lanes 10..15 contribute 0)
    #pragma unroll
    for (int q = 0; q < 12; ++q) {
        float v = comps[q];
        v += __shfl_xor(v, 1, 64); v += __shfl_xor(v, 2, 64);
        v += __shfl_xor(v, 4, 64); v += __shfl_xor(v, 8, 64);
        comps[q] = v;
    }
    {
        float ps = (lane < 10) ? psum : 0.f;
        ps += __shfl_xor(ps, 1, 64); ps += __shfl_xor(ps, 2, 64);
        ps += __shfl_xor(ps, 4, 64); ps += __shfl_xor(ps, 8, 64);
        if (lane == 0) {
            #pragma unroll
            for (int q = 0; q < 12; ++q) sG[bb][w][q] = comps[q];
            sPsum[bb][w] = ps;
        }
    }
    __syncthreads();

    // energy per pair
    if (lane < 10) {
        const float S2 = sPsum[bb][0] + sPsum[bb][1];
        outBase[(size_t)Bn * 6 + o] = S2 * fcv;
    }

    // force + torque per b (lane 0 of wave w==0)
    if (w == 0 && lane == 0) {
        float Gq[12];
        #pragma unroll
        for (int q = 0; q < 12; ++q) Gq[q] = sG[bb][0][q] + sG[bb][1][q];
        float* out_force  = outBase;
        float* out_torque = outBase + (size_t)Bn * 3;
        out_force[b * 3 + 0] = Gq[0];
        out_force[b * 3 + 1] = Gq[1];
        out_force[b * 3 + 2] = Gq[2];
        float t0 = 0.f, t1 = 0.f, t2 = 0.f;
        #pragma unroll
        for (int jj = 0; jj < 3; ++jj) {
            float u0 = Gq[3 + 0 * 3 + jj], u1 = Gq[3 + 1 * 3 + jj], u2 = Gq[3 + 2 * 3 + jj];
            float v0 = O[0 * 3 + jj], v1 = O[1 * 3 + jj], v2 = O[2 * 3 + jj];
            t0 += u1 * v2 - u2 * v1;
            t1 += u2 * v0 - u0 * v2;
            t2 += u0 * v1 - u1 * v0;
        }
        out_torque[b * 3 + 0] = t0;
        out_torque[b * 3 + 1] = t1;
        out_torque[b * 3 + 2] = t2;
    }
}

extern "C" void kernel_launch(void* const* d_in, const int* in_sizes, int n_in,
                              void* d_out, int out_size, void* d_ws, size_t ws_size,
                              hipStream_t stream) {
    const float* dr            = (const float*)d_in[0];
    const float* orientation   = (const float*)d_in[1];
    const float* n_orientation = (const float*)d_in[2];
    const float* W0 = (const float*)d_in[3];
    const float* b0 = (const float*)d_in[4];
    const float* W1 = (const float*)d_in[5];
    const float* b1 = (const float*)d_in[6];
    const float* W2 = (const float*)d_in[7];
    const float* b2 = (const float*)d_in[8];
    const float* f1 = (const float*)d_in[9];
    const float* f2 = (const float*)d_in[10];

    const int B = in_sizes[0] / (NB * 3);   // 32768

    float* out = (float*)d_out;

    float* ws_R  = (float*)d_ws;
    float* ws_fc = ws_R + (size_t)B * NSEL;
    float* ws_F  = ws_fc + (size_t)B * NSEL;

    const size_t needed_pre = sizeof(float) * ((size_t)B * 281 + WSWN);
    const bool pre = ws_size >= needed_pre;

    if (pre) {
        float* ws_ndn = ws_F + B;
        float* ws_nor = ws_ndn + (size_t)B * NSEL * 3;
        float* wsW    = ws_nor + (size_t)B * NSEL * 9;
        sel_kernel<<<B / 4, 256, 0, stream>>>(dr, n_orientation,
                                              W0, b0, W1, b1, W2, b2, f1, f2,
                                              ws_R, ws_fc, ws_F, nullptr,
                                              ws_ndn, ws_nor, wsW);
        energy_kernel_t<true><<<B / 4, 512, 0, stream>>>(
            orientation, n_orientation, wsW, ws_R, nullptr, nullptr, out, B);
    } else {
        int*   ws_idx = (int*)(ws_F + B);
        float* ws_ndn = (float*)(ws_idx + (size_t)B * NSEL);
        float* wsW    = ws_ndn + (size_t)B * NSEL * 3;
        sel_kernel<<<B / 4, 256, 0, stream>>>(dr, n_orientation,
                                              W0, b0, W1, b1, W2, b2, f1, f2,
                                              ws_R, ws_fc, ws_F, ws_idx,
                                              ws_ndn, nullptr, wsW);
        energy_kernel_t<false><<<B / 4, 512, 0, stream>>>(
            orientation, n_orientation, wsW, ws_R, ws_idx, ws_ndn, out, B);
    }
}